// Round 10
// baseline (381.970 us; speedup 1.0000x reference)
//
#include <hip/hip_runtime.h>
#include <hip/hip_bf16.h>
#include <hip/hip_fp16.h>

typedef _Float16 f16;
typedef _Float16 f16x8 __attribute__((ext_vector_type(8)));
typedef float f32x4 __attribute__((ext_vector_type(4)));

#define SP 16384             // 128*128 spatial per batch
#define NTILES 4096          // 16-spatial tiles total (4 batches * 1024)
#define XF_BYTES ((size_t)NTILES * 40960)

// xf tile layout (40 KB per 16-spatial tile, fragment-ready, LANE-LINEAR):
//   byte = t*8192 + k0*1024 + g4*256 + c*16 + e*2
//   holds x[t, d=k0*32+g4*8+e, s=tile*16+c]
// Wave b128 fragment read = contiguous 1024B block: conflict-free.

__global__ void prep_weights(const float* __restrict__ Wq,
                             const float* __restrict__ Wkv,
                             const float* __restrict__ Wp,
                             f16* __restrict__ wqT,
                             f16* __restrict__ wkvT,
                             f16* __restrict__ wpT) {
  const int f = threadIdx.x;
  const int k = blockIdx.x;
  wkvT[f * 256 + k] = (f16)Wkv[k * 512 + f];
  if (f < 256) {
    wqT[f * 256 + k] = (f16)Wq[k * 256 + f];
    wpT[f * 256 + k] = (f16)Wp[k * 256 + f];
  }
}

// Kernel A: transpose/cast x -> xf (fragment layout), full input.
__global__ __launch_bounds__(256) void xpose(const float* __restrict__ x,
                                             f16* __restrict__ xf) {
  __shared__ float ls[32 * 258];
  const int blk = blockIdx.x;
  const int sg = blk & 63;          // s-chunk of 256
  const int k0 = (blk >> 6) & 7;    // d-chunk of 32
  const int t  = (blk >> 9) % 5;
  const int bl = blk / 2560;        // batch 0..3
  const int tid = threadIdx.x;

  const float* xA = x + ((size_t)((bl * 5 + t) * 256 + k0 * 32)) * SP + sg * 256;
#pragma unroll
  for (int j = 0; j < 8; ++j) {
    const int qq = j * 256 + tid;
    const int dl = qq >> 6, s4 = qq & 63;
    const f32x4 v = *(const f32x4*)(xA + (size_t)dl * SP + s4 * 4);
    *(f32x4*)&ls[dl * 258 + s4 * 4] = v;
  }
  __syncthreads();

  const int tile_base = bl * 1024 + sg * 16;
#pragma unroll
  for (int pp = 0; pp < 4; ++pp) {
    const int piece = pp * 256 + tid;
    const int tt = piece >> 6;
    const int c  = (piece >> 2) & 15;
    const int g4 = piece & 3;
    f16x8 pk;
#pragma unroll
    for (int e = 0; e < 8; ++e)
      pk[e] = (f16)ls[(g4 * 8 + e) * 258 + tt * 16 + c];
    f16* dst = xf + (size_t)(tile_base + tt) * 20480 + t * 4096 + k0 * 512
                  + g4 * 128 + c * 8;
    *(f16x8*)dst = pk;
  }
}

// Kernel B: 1 tile per block, wave = 2 heads. U=1 keeps acc at 88 regs ->
// fits 170-reg cap (launch_bounds(512,3)): 3 waves/SIMD + 3 blocks/CU of
// phase-desynced overlap. Bias constants load AFTER the k-loop.
__global__ __launch_bounds__(512, 3) void fused_attn(
    const f16* __restrict__ xf,
    const float* __restrict__ bq,
    const float* __restrict__ bkv,
    const float* __restrict__ bp,
    const float* __restrict__ pos_bias,
    const f16* __restrict__ wqT,
    const f16* __restrict__ wkvT,
    const f16* __restrict__ wpT,
    float* __restrict__ out) {
  __shared__ f16 fb[5 * 16 * 256];  // 40 KB fragment tile
  __shared__ f16 as_[16 * 256];     // 8 KB attn-out (lane-linear)

  const int tid = threadIdx.x;
  const int lane = tid & 63;
  const int w = tid >> 6;    // wave 0..7 -> heads 2w, 2w+1
  const int c = lane & 15;
  const int g4 = lane >> 4;
  const int hA = 2 * w;

  // ---- stage tile: 10 x global_load_lds(16B) per wave ----
  {
    const char* src = (const char*)xf + (size_t)blockIdx.x * 40960
                      + w * 5120 + lane * 16;
    char* dst = (char*)fb + w * 5120 + lane * 16;
#pragma unroll
    for (int n = 0; n < 10; ++n) {
      __builtin_amdgcn_global_load_lds(
          (const void __attribute__((address_space(1)))*)(src + n * 512),
          (void __attribute__((address_space(3)))*)(dst + n * 512), 16, 0, 0);
    }
  }

  const f16* wqp0 = wqT + (hA * 16 + c) * 256;
  const f16* wqp1 = wqT + ((hA + 1) * 16 + c) * 256;
  const f16* wkp0 = wkvT + (hA * 16 + c) * 256;
  const f16* wkp1 = wkvT + ((hA + 1) * 16 + c) * 256;
  const f16* wvp0 = wkvT + (256 + hA * 16 + c) * 256;
  const f16* wvp1 = wkvT + (256 + (hA + 1) * 16 + c) * 256;

  __syncthreads();  // drains gll: fb ready

  // ---- q/k/v GEMM (swapped operands: C[m=dk][n=s]) ----
  f32x4 qacc[2] = {};
  f32x4 kacc[2][5] = {};
  f32x4 vacc[2][5] = {};
#pragma unroll 1
  for (int k0 = 0; k0 < 8; ++k0) {
    const int kk = (k0 << 5) + (g4 << 3);
    const f16x8 fq0 = *(const f16x8*)(wqp0 + kk);
    const f16x8 fq1 = *(const f16x8*)(wqp1 + kk);
    const f16x8 fk0 = *(const f16x8*)(wkp0 + kk);
    const f16x8 fk1 = *(const f16x8*)(wkp1 + kk);
    const f16x8 fv0 = *(const f16x8*)(wvp0 + kk);
    const f16x8 fv1 = *(const f16x8*)(wvp1 + kk);
    const int base = (k0 << 10) + (g4 << 8) + (c << 4);  // lane-linear
    const char* fbp = (const char*)fb;
    f16x8 xfr[5];
#pragma unroll
    for (int t = 0; t < 5; ++t) xfr[t] = *(const f16x8*)(fbp + (t << 13) + base);

    qacc[0] = __builtin_amdgcn_mfma_f32_16x16x32_f16(fq0, xfr[0], qacc[0], 0, 0, 0);
    qacc[1] = __builtin_amdgcn_mfma_f32_16x16x32_f16(fq1, xfr[0], qacc[1], 0, 0, 0);
#pragma unroll
    for (int t = 0; t < 5; ++t) {
      kacc[0][t] = __builtin_amdgcn_mfma_f32_16x16x32_f16(fk0, xfr[t], kacc[0][t], 0, 0, 0);
      kacc[1][t] = __builtin_amdgcn_mfma_f32_16x16x32_f16(fk1, xfr[t], kacc[1][t], 0, 0, 0);
      vacc[0][t] = __builtin_amdgcn_mfma_f32_16x16x32_f16(fv0, xfr[t], vacc[0][t], 0, 0, 0);
      vacc[1][t] = __builtin_amdgcn_mfma_f32_16x16x32_f16(fv1, xfr[t], vacc[1][t], 0, 0, 0);
    }
  }

  // ---- per-head constants (loaded late: k-loop live set stays small) ----
  float pb[2][5], bqr[2][4], bkr[2][4], bvr[2][4];
#pragma unroll
  for (int j = 0; j < 2; ++j) {
    const int hj = hA + j;
#pragma unroll
    for (int t = 0; t < 5; ++t) pb[j][t] = pos_bias[hj * 5 + t];
#pragma unroll
    for (int rr = 0; rr < 4; ++rr) {
      bqr[j][rr] = bq[hj * 16 + 4 * g4 + rr];
      bkr[j][rr] = bkv[hj * 16 + 4 * g4 + rr];
      bvr[j][rr] = bkv[256 + hj * 16 + 4 * g4 + rr];
    }
  }

  // ---- attention (lane holds q/k/v[dk=4g4+rr][s=c]) ----
#pragma unroll
  for (int j = 0; j < 2; ++j) {
    float qv[4];
#pragma unroll
    for (int rr = 0; rr < 4; ++rr) qv[rr] = qacc[j][rr] + bqr[j][rr];
    float sc[5];
#pragma unroll
    for (int t = 0; t < 5; ++t) {
      float p = 0.f;
#pragma unroll
      for (int rr = 0; rr < 4; ++rr) p += qv[rr] * (kacc[j][t][rr] + bkr[j][rr]);
      p += __shfl_xor(p, 16);
      p += __shfl_xor(p, 32);
      sc[t] = p * 4.0f + pb[j][t];  // /temperature (=0.25) + pos_bias
    }
    float m = sc[0];
#pragma unroll
    for (int t = 1; t < 5; ++t) m = fmaxf(m, sc[t]);
    float l = 0.f;
#pragma unroll
    for (int t = 0; t < 5; ++t) { sc[t] = __expf(sc[t] - m); l += sc[t]; }
    const float inv = 1.0f / l;
    // attn_out[feat=(2w+j)*16+4g4+rr][s=c]: one aligned b64 write (2-way max)
    union { f16 hh[4]; unsigned long long uu; } pk;
#pragma unroll
    for (int rr = 0; rr < 4; ++rr) {
      float o = 0.f;
#pragma unroll
      for (int t = 0; t < 5; ++t) o += sc[t] * (vacc[j][t][rr] + bvr[j][rr]);
      pk.hh[rr] = (f16)(o * inv);
    }
    const int byte = (w << 10) + ((2 * j + (g4 >> 1)) << 8) + (c << 4)
                     + ((g4 & 1) << 3);
    *(unsigned long long*)((char*)as_ + byte) = pk.uu;
  }
  __syncthreads();  // as_ visible

  // ---- projection: attn_out[16s x 256] @ Wp ----
  const f16* wpp0 = wpT + (hA * 16 + c) * 256;
  const f16* wpp1 = wpT + ((hA + 1) * 16 + c) * 256;
  f32x4 facc[2] = {};
#pragma unroll 1
  for (int k0 = 0; k0 < 8; ++k0) {
    const int kk = (k0 << 5) + (g4 << 3);
    const f16x8 f0 = *(const f16x8*)(wpp0 + kk);
    const f16x8 f1 = *(const f16x8*)(wpp1 + kk);
    const f16x8 af = *(const f16x8*)((const char*)as_ + (k0 << 10) + (g4 << 8)
                                     + (c << 4));
    facc[0] = __builtin_amdgcn_mfma_f32_16x16x32_f16(af, f0, facc[0], 0, 0, 0);
    facc[1] = __builtin_amdgcn_mfma_f32_16x16x32_f16(af, f1, facc[1], 0, 0, 0);
  }

  // ---- store ----
  {
    const int g = blockIdx.x;
    const int b = g >> 10, s0 = (g & 1023) << 4;
#pragma unroll
    for (int j = 0; j < 2; ++j) {
      const int dg = (hA + j) * 16 + c;
      f32x4 vs = facc[j];
      const float bias = bp[dg];
#pragma unroll
      for (int rr = 0; rr < 4; ++rr) vs[rr] += bias;
      float* dst = out + ((size_t)b * 256 + dg) * SP + s0 + (g4 << 2);
      *(f32x4*)dst = vs;
    }
  }
}

extern "C" void kernel_launch(void* const* d_in, const int* in_sizes, int n_in,
                              void* d_out, int out_size, void* d_ws, size_t ws_size,
                              hipStream_t stream) {
  const float* x   = (const float*)d_in[0];
  const float* Wq  = (const float*)d_in[1];
  const float* bq  = (const float*)d_in[2];
  const float* Wkv = (const float*)d_in[3];
  const float* bkv = (const float*)d_in[4];
  const float* Wp  = (const float*)d_in[5];
  const float* bp  = (const float*)d_in[6];
  const float* pos = (const float*)d_in[7];

  f16* xf   = (f16*)d_ws;                      // 168 MB
  f16* wqT  = (f16*)((char*)d_ws + XF_BYTES);
  f16* wkvT = wqT + 256 * 256;
  f16* wpT  = wkvT + 512 * 256;

  prep_weights<<<256, 512, 0, stream>>>(Wq, Wkv, Wp, wqT, wkvT, wpT);
  xpose<<<10240, 256, 0, stream>>>(x, xf);
  fused_attn<<<NTILES, 512, 0, stream>>>(xf, bq, bkv, bp, pos,
                                         wqT, wkvT, wpT, (float*)d_out);
}

// Round 11
// 372.029 us; speedup vs baseline: 1.0267x; 1.0267x over previous
//
#include <hip/hip_runtime.h>
#include <hip/hip_bf16.h>
#include <hip/hip_fp16.h>

typedef _Float16 f16;
typedef _Float16 f16x8 __attribute__((ext_vector_type(8)));
typedef float f32x4 __attribute__((ext_vector_type(4)));

#define SP 16384             // 128*128 spatial per batch
#define NTILES 4096          // 16-spatial tiles total (4 batches * 1024)
#define XF_BYTES ((size_t)NTILES * 40960)

// xf tile layout (40 KB per 16-spatial tile, fragment-ready, LANE-LINEAR):
//   byte = t*8192 + k0*1024 + g4*256 + c*16 + e*2
//   holds x[t, d=k0*32+g4*8+e, s=tile*16+c]
// ao tile layout (8 KB per tile, proj-A-fragment-ready, LANE-LINEAR):
//   byte(feat,s) = (feat>>5)*1024 + ((feat>>3)&3)*256 + s*16 + (feat&7)*2

__global__ void prep_weights(const float* __restrict__ Wq,
                             const float* __restrict__ Wkv,
                             const float* __restrict__ Wp,
                             f16* __restrict__ wqT,
                             f16* __restrict__ wkvT,
                             f16* __restrict__ wpT) {
  const int f = threadIdx.x;
  const int k = blockIdx.x;
  wkvT[f * 256 + k] = (f16)Wkv[k * 512 + f];
  if (f < 256) {
    wqT[f * 256 + k] = (f16)Wq[k * 256 + f];
    wpT[f * 256 + k] = (f16)Wp[k * 256 + f];
  }
}

// Kernel A: transpose/cast x -> xf (fragment layout), full input.
__global__ __launch_bounds__(256) void xpose(const float* __restrict__ x,
                                             f16* __restrict__ xf) {
  __shared__ float ls[32 * 258];
  const int blk = blockIdx.x;
  const int sg = blk & 63;          // s-chunk of 256
  const int k0 = (blk >> 6) & 7;    // d-chunk of 32
  const int t  = (blk >> 9) % 5;
  const int bl = blk / 2560;        // batch 0..3
  const int tid = threadIdx.x;

  const float* xA = x + ((size_t)((bl * 5 + t) * 256 + k0 * 32)) * SP + sg * 256;
#pragma unroll
  for (int j = 0; j < 8; ++j) {
    const int qq = j * 256 + tid;
    const int dl = qq >> 6, s4 = qq & 63;
    const f32x4 v = *(const f32x4*)(xA + (size_t)dl * SP + s4 * 4);
    *(f32x4*)&ls[dl * 258 + s4 * 4] = v;
  }
  __syncthreads();

  const int tile_base = bl * 1024 + sg * 16;
#pragma unroll
  for (int pp = 0; pp < 4; ++pp) {
    const int piece = pp * 256 + tid;
    const int tt = piece >> 6;
    const int c  = (piece >> 2) & 15;
    const int g4 = piece & 3;
    f16x8 pk;
#pragma unroll
    for (int e = 0; e < 8; ++e)
      pk[e] = (f16)ls[(g4 * 8 + e) * 258 + tt * 16 + c];
    f16* dst = xf + (size_t)(tile_base + tt) * 20480 + t * 4096 + k0 * 512
                  + g4 * 128 + c * 8;
    *(f16x8*)dst = pk;
  }
}

// Kernel B: qkv GEMM + attention only (projection split out). Wave = 1 head,
// block = 1 tile x 8-head group. acc=44 -> unified ~104 fits (512,4) cap 128
// -> 4 waves/SIMD -> TWO resident blocks/CU (LDS 40 KB): block n+1's stage
// and k-loop overlap block n's attention/store. Single barrier.
__global__ __launch_bounds__(512, 4) void qkv_attn(
    const f16* __restrict__ xf,
    const float* __restrict__ bq,
    const float* __restrict__ bkv,
    const float* __restrict__ pos_bias,
    const f16* __restrict__ wqT,
    const f16* __restrict__ wkvT,
    f16* __restrict__ ao) {
  __shared__ f16 fb[5 * 16 * 256];  // 40 KB fragment tile

  const int tid = threadIdx.x;
  const int lane = tid & 63;
  const int w = tid >> 6;         // wave 0..7
  const int c = lane & 15;        // spatial s within tile
  const int g4 = lane >> 4;       // k-group / dk-group
  const int blk = blockIdx.x;
  const int tile = blk >> 1;
  const int h = ((blk & 1) << 3) + w;  // head 0..15

  // ---- stage tile: 10 x global_load_lds(16B) per wave ----
  {
    const char* src = (const char*)xf + (size_t)tile * 40960 + w * 5120
                      + lane * 16;
    char* dst = (char*)fb + w * 5120 + lane * 16;
#pragma unroll
    for (int n = 0; n < 10; ++n) {
      __builtin_amdgcn_global_load_lds(
          (const void __attribute__((address_space(1)))*)(src + n * 512),
          (void __attribute__((address_space(3)))*)(dst + n * 512), 16, 0, 0);
    }
  }

  const f16* wqp = wqT + (h * 16 + c) * 256;
  const f16* wkp = wkvT + (h * 16 + c) * 256;
  const f16* wvp = wkvT + (256 + h * 16 + c) * 256;

  __syncthreads();  // drains gll: fb ready

  // ---- q/k/v GEMM (swapped operands: C[m=dk][n=s]) ----
  f32x4 qa = {};
  f32x4 ka[5] = {};
  f32x4 va[5] = {};
#pragma unroll 1
  for (int k0 = 0; k0 < 8; ++k0) {
    const int kk = (k0 << 5) + (g4 << 3);
    const f16x8 fq = *(const f16x8*)(wqp + kk);
    const f16x8 fk = *(const f16x8*)(wkp + kk);
    const f16x8 fv = *(const f16x8*)(wvp + kk);
    const int base = (k0 << 10) + (g4 << 8) + (c << 4);  // lane-linear
    const char* fbp = (const char*)fb;
    f16x8 xfr[5];
#pragma unroll
    for (int t = 0; t < 5; ++t) xfr[t] = *(const f16x8*)(fbp + (t << 13) + base);

    qa = __builtin_amdgcn_mfma_f32_16x16x32_f16(fq, xfr[0], qa, 0, 0, 0);
#pragma unroll
    for (int t = 0; t < 5; ++t) {
      ka[t] = __builtin_amdgcn_mfma_f32_16x16x32_f16(fk, xfr[t], ka[t], 0, 0, 0);
      va[t] = __builtin_amdgcn_mfma_f32_16x16x32_f16(fv, xfr[t], va[t], 0, 0, 0);
    }
  }

  // ---- per-head constants (late load keeps k-loop live set small) ----
  float pb[5], bqr[4], bkr[4], bvr[4];
#pragma unroll
  for (int t = 0; t < 5; ++t) pb[t] = pos_bias[h * 5 + t];
#pragma unroll
  for (int rr = 0; rr < 4; ++rr) {
    bqr[rr] = bq[h * 16 + 4 * g4 + rr];
    bkr[rr] = bkv[h * 16 + 4 * g4 + rr];
    bvr[rr] = bkv[256 + h * 16 + 4 * g4 + rr];
  }

  // ---- attention (lane holds q/k/v[dk=4g4+rr][s=c]) ----
  float qv[4];
#pragma unroll
  for (int rr = 0; rr < 4; ++rr) qv[rr] = qa[rr] + bqr[rr];
  float sc[5];
#pragma unroll
  for (int t = 0; t < 5; ++t) {
    float p = 0.f;
#pragma unroll
    for (int rr = 0; rr < 4; ++rr) p += qv[rr] * (ka[t][rr] + bkr[rr]);
    p += __shfl_xor(p, 16);
    p += __shfl_xor(p, 32);
    sc[t] = p * 4.0f + pb[t];  // /temperature (=0.25) + pos_bias
  }
  float m = sc[0];
#pragma unroll
  for (int t = 1; t < 5; ++t) m = fmaxf(m, sc[t]);
  float l = 0.f;
#pragma unroll
  for (int t = 0; t < 5; ++t) { sc[t] = __expf(sc[t] - m); l += sc[t]; }
  const float inv = 1.0f / l;
  union { f16 hh[4]; unsigned long long uu; } pk;
#pragma unroll
  for (int rr = 0; rr < 4; ++rr) {
    float o = 0.f;
#pragma unroll
    for (int t = 0; t < 5; ++t) o += sc[t] * (va[t][rr] + bvr[rr]);
    pk.hh[rr] = (f16)(o * inv);
  }
  // ao[feat=16h+4g4+rr][s=c] in proj-fragment layout, one aligned b64 store
  const int byte = ((h >> 1) << 10) + (((2 * h + (g4 >> 1)) & 3) << 8)
                   + (c << 4) + ((g4 & 1) << 3);
  *(unsigned long long*)((char*)ao + (size_t)tile * 8192 + byte) = pk.uu;
}

// Kernel C: projection GEMM. Block = 1 tile; wave w -> douts 32w..32w+31.
// acc=8, live ~55 -> (512,6): 6 waves/SIMD, LDS 8 KB -> high occupancy.
__global__ __launch_bounds__(512, 6) void proj(
    const f16* __restrict__ ao,
    const f16* __restrict__ wpT,
    const float* __restrict__ bp,
    float* __restrict__ out) {
  __shared__ f16 as_[16 * 256];  // 8 KB attn-out tile

  const int tid = threadIdx.x;
  const int lane = tid & 63;
  const int w = tid >> 6;
  const int c = lane & 15;
  const int g4 = lane >> 4;
  const int g = blockIdx.x;

  // ---- stage ao tile: 1 gll(16B) per thread ----
  {
    const char* src = (const char*)ao + (size_t)g * 8192 + w * 1024 + lane * 16;
    char* dst = (char*)as_ + w * 1024 + lane * 16;
    __builtin_amdgcn_global_load_lds(
        (const void __attribute__((address_space(1)))*)src,
        (void __attribute__((address_space(3)))*)dst, 16, 0, 0);
  }

  const f16* wpp0 = wpT + (32 * w + c) * 256;
  const f16* wpp1 = wpT + (32 * w + 16 + c) * 256;

  __syncthreads();  // drains gll: as_ ready

  f32x4 facc0 = {}, facc1 = {};
#pragma unroll 1
  for (int k0 = 0; k0 < 8; ++k0) {
    const int kk = (k0 << 5) + (g4 << 3);
    const f16x8 f0 = *(const f16x8*)(wpp0 + kk);
    const f16x8 f1 = *(const f16x8*)(wpp1 + kk);
    const f16x8 af = *(const f16x8*)((const char*)as_ + (k0 << 10) + (g4 << 8)
                                     + (c << 4));
    facc0 = __builtin_amdgcn_mfma_f32_16x16x32_f16(af, f0, facc0, 0, 0, 0);
    facc1 = __builtin_amdgcn_mfma_f32_16x16x32_f16(af, f1, facc1, 0, 0, 0);
  }

  // ---- store: out[b, dout, s0 + 4*g4 + rr] ----
  const int b = g >> 10, s0 = (g & 1023) << 4;
  {
    const int dg = 32 * w + c;
    const float bias = bp[dg];
    f32x4 vs = facc0;
#pragma unroll
    for (int rr = 0; rr < 4; ++rr) vs[rr] += bias;
    *(f32x4*)(out + ((size_t)b * 256 + dg) * SP + s0 + (g4 << 2)) = vs;
  }
  {
    const int dg = 32 * w + 16 + c;
    const float bias = bp[dg];
    f32x4 vs = facc1;
#pragma unroll
    for (int rr = 0; rr < 4; ++rr) vs[rr] += bias;
    *(f32x4*)(out + ((size_t)b * 256 + dg) * SP + s0 + (g4 << 2)) = vs;
  }
}

extern "C" void kernel_launch(void* const* d_in, const int* in_sizes, int n_in,
                              void* d_out, int out_size, void* d_ws, size_t ws_size,
                              hipStream_t stream) {
  const float* x   = (const float*)d_in[0];
  const float* Wq  = (const float*)d_in[1];
  const float* bq  = (const float*)d_in[2];
  const float* Wkv = (const float*)d_in[3];
  const float* bkv = (const float*)d_in[4];
  const float* Wp  = (const float*)d_in[5];
  const float* bp  = (const float*)d_in[6];
  const float* pos = (const float*)d_in[7];

  f16* xf   = (f16*)d_ws;                      // 168 MB
  f16* wqT  = (f16*)((char*)d_ws + XF_BYTES);  // 64 K f16
  f16* wkvT = wqT + 256 * 256;                 // 128 K f16
  f16* wpT  = wkvT + 512 * 256;                // 64 K f16
  f16* ao   = wpT + 256 * 256;                 // 16.8 M f16 = 33.5 MB

  prep_weights<<<256, 512, 0, stream>>>(Wq, Wkv, Wp, wqT, wkvT, wpT);
  xpose<<<10240, 256, 0, stream>>>(x, xf);
  qkv_attn<<<NTILES * 2, 512, 0, stream>>>(xf, bq, bkv, pos, wqT, wkvT, ao);
  proj<<<NTILES, 512, 0, stream>>>(ao, wpT, bp, (float*)d_out);
}